// Round 7
// baseline (3289.970 us; speedup 1.0000x reference)
//
#include <hip/hip_runtime.h>

// ---------------- problem constants ----------------
#define T_STEPS 512
#define BATCH_N 256
#define IDIM    128
#define NDIM    1024
#define ODIM    10

// 128 WGs = 16 batch-groups (16 rows) x 8 col-slices (128 cols), 512 threads
// (8 waves, K-split 8). Cross-WG y exchange: self-tagged u32 {bf16<<16|tag},
// parity double-buffered, sc0 sc1 (device scope) both ways — the R5-proven
// protocol. No flags, no drains, no scope tricks (R4/R6 both hung on those).
#define THREADS 512
#define GAIN 0.03125f

// ---------------- workspace layout (bytes) ----------------
#define YBUF_OFF    (33554432ull)                 // after bf16 batch [512][256][128]
#define YBUF_WORDS  (2ull*16*16*1024)             // u32 [parity][group][row][n]
#define XT_OFF      (YBUF_OFF + YBUF_WORDS*4ull)  // 35,651,584
#define XT_BYTES    (1048576ull)                  // fp32 [256][1024]
#define WS_NEED     (XT_OFF + XT_BYTES)

#define PAR_STRIDE  262144                        // u32 elements per parity

typedef short    s16x8 __attribute__((ext_vector_type(8)));
typedef float    f32x4 __attribute__((ext_vector_type(4)));
typedef unsigned u32x4 __attribute__((ext_vector_type(4)));

__device__ __forceinline__ unsigned short f2bf(float f) {
  unsigned u = __builtin_bit_cast(unsigned, f);
  u += 0x7fffu + ((u >> 16) & 1u);               // RTNE
  return (unsigned short)(u >> 16);
}
__device__ __forceinline__ unsigned umin2(unsigned a, unsigned b) { return a < b ? a : b; }

// ---------------- batch fp32 -> bf16 prepass ----------------
__global__ void horn_convert(const float* __restrict__ src, unsigned short* __restrict__ dst) {
  size_t gid = (size_t)blockIdx.x * 256 + threadIdx.x;
  const f32x4* s4 = reinterpret_cast<const f32x4*>(src) + gid * 2;
  f32x4 a = s4[0], b = s4[1];
  u32x4 o;
  o[0] = (unsigned)f2bf(a[0]) | ((unsigned)f2bf(a[1]) << 16);
  o[1] = (unsigned)f2bf(a[2]) | ((unsigned)f2bf(a[3]) << 16);
  o[2] = (unsigned)f2bf(b[0]) | ((unsigned)f2bf(b[1]) << 16);
  o[3] = (unsigned)f2bf(b[2]) | ((unsigned)f2bf(b[3]) << 16);
  reinterpret_cast<u32x4*>(dst)[gid] = o;
}

// ---------------- persistent recurrent kernel ----------------
// LDS: [0,131072)  red[2 parity][8 wv][8 ct][64 lane] f32x4
//      [131072,163840) i2h B-frags s16x8 [8 ct][4 kc][64 lane]
__launch_bounds__(THREADS, 1)
__global__ void horn_persistent(const unsigned short* __restrict__ batchbf,
                                const float* __restrict__ i2h_w,
                                const float* __restrict__ i2h_b,
                                const float* __restrict__ h2h_w,
                                const float* __restrict__ h2h_b,
                                unsigned* ybuf,           // u32 [2][16][16][1024]
                                float* xT)                // [256][1024] fp32
{
  extern __shared__ char smem[];
  f32x4* red = (f32x4*)smem;                       // 128 KB
  s16x8* i2l = (s16x8*)(smem + 131072);            // 32 KB

  const int tid  = threadIdx.x;
  const int lane = tid & 63;
  const int wv   = tid >> 6;            // wave 0..7: K-eighth [wv*128, wv*128+128)
  const int g    = blockIdx.x & 15;     // batch group (16 rows)
  const int s    = blockIdx.x >> 4;     // col-slice 0..7 (128 cols)
  const int l15  = lane & 15;
  const int kb   = lane >> 4;
  const int jc   = s * 128 + wv * 16 + l15;        // owned output column (ct = wv)

  // ---- W fragments in VGPRs: 8 col-tiles x 4 k-frags (K-eighth wv), xGAIN ----
  s16x8 wfrag[8][4];
  #pragma unroll
  for (int ct = 0; ct < 8; ++ct) {
    #pragma unroll
    for (int kc = 0; kc < 4; ++kc) {
      const float* gp = h2h_w + (size_t)(s * 128 + ct * 16 + l15) * NDIM + wv * 128 + kc * 32 + kb * 8;
      f32x4 a = *reinterpret_cast<const f32x4*>(gp);
      f32x4 b = *reinterpret_cast<const f32x4*>(gp + 4);
      s16x8 v;
      v[0] = (short)f2bf(a[0]*GAIN); v[1] = (short)f2bf(a[1]*GAIN);
      v[2] = (short)f2bf(a[2]*GAIN); v[3] = (short)f2bf(a[3]*GAIN);
      v[4] = (short)f2bf(b[0]*GAIN); v[5] = (short)f2bf(b[1]*GAIN);
      v[6] = (short)f2bf(b[2]*GAIN); v[7] = (short)f2bf(b[3]*GAIN);
      wfrag[ct][kc] = v;
    }
  }

  // ---- i2h B-frags -> LDS: entry e = (ct*4+kc)*64 + ln ----
  for (int e = tid; e < 2048; e += THREADS) {
    int ct = e >> 8, kc = (e >> 6) & 3, ln = e & 63;
    int col = s * 128 + ct * 16 + (ln & 15);
    int k0  = kc * 32 + (ln >> 4) * 8;
    const float* gp = i2h_w + (size_t)col * IDIM + k0;
    s16x8 v;
    #pragma unroll
    for (int q = 0; q < 8; ++q) v[q] = (short)f2bf(gp[q]);
    i2l[e] = v;
  }
  const float bias = i2h_b[jc] + GAIN * h2h_b[jc];
  __syncthreads();

  // ---- batch A-frags for t=0 (full IDIM, 4 chunks) ----
  s16x8 bfr[4];
  {
    const unsigned short* bp = batchbf + ((size_t)g * 16 + l15) * IDIM + kb * 8;
    #pragma unroll
    for (int kc = 0; kc < 4; ++kc) bfr[kc] = *reinterpret_cast<const s16x8*>(bp + kc * 32);
  }

  float xs[4] = {0.f,0.f,0.f,0.f};
  float ys[4] = {0.f,0.f,0.f,0.f};

  // per-lane pointers (word units)
  const unsigned* gbase = ybuf + (size_t)(g * 16 + l15) * 1024 + wv * 128 + kb * 8;
  unsigned* pbase = ybuf + (size_t)(g * 16 + kb * 4) * 1024 + jc;

  for (int t = 0; t < T_STEPS; ++t) {
    const int p = t & 1, pn = p ^ 1;

    // ---- u-partial for owned ct=wv: uacc = batch_t @ i2h^T (4 MFMAs) ----
    f32x4 uacc = {0,0,0,0};
    #pragma unroll
    for (int kc = 0; kc < 4; ++kc)
      uacc = __builtin_amdgcn_mfma_f32_16x16x32_bf16(bfr[kc], i2l[(wv * 4 + kc) * 64 + lane], uacc, 0, 0, 0);

    // ---- poll+gather: self-tagged words, re-load until all tags >= t ----
    const unsigned* gp = gbase + (size_t)p * PAR_STRIDE;
    u32x4 g0, g1, g2, g3, g4, g5, g6, g7;
    while (true) {
      asm volatile(
        "global_load_dwordx4 %0, %8, off offset:0   sc0 sc1\n\t"
        "global_load_dwordx4 %1, %8, off offset:16  sc0 sc1\n\t"
        "global_load_dwordx4 %2, %8, off offset:128 sc0 sc1\n\t"
        "global_load_dwordx4 %3, %8, off offset:144 sc0 sc1\n\t"
        "global_load_dwordx4 %4, %8, off offset:256 sc0 sc1\n\t"
        "global_load_dwordx4 %5, %8, off offset:272 sc0 sc1\n\t"
        "global_load_dwordx4 %6, %8, off offset:384 sc0 sc1\n\t"
        "global_load_dwordx4 %7, %8, off offset:400 sc0 sc1\n\t"
        "s_waitcnt vmcnt(0)"
        : "=&v"(g0), "=&v"(g1), "=&v"(g2), "=&v"(g3),
          "=&v"(g4), "=&v"(g5), "=&v"(g6), "=&v"(g7)
        : "v"(gp) : "memory");
      unsigned mn = 0xffffffffu;
      #define MN(v) mn = umin2(mn, umin2(umin2(v[0]&0xffffu, v[1]&0xffffu), umin2(v[2]&0xffffu, v[3]&0xffffu)));
      MN(g0) MN(g1) MN(g2) MN(g3) MN(g4) MN(g5) MN(g6) MN(g7)
      #undef MN
      if (__all((int)(mn >= (unsigned)t))) break;
      __builtin_amdgcn_s_sleep(2);
    }

    // ---- repack tagged u32 -> bf16 A-frags (hi16 of each word) ----
    s16x8 a0, a1, a2, a3;
    #define RPK(dst, lo, hi) { u32x4 o_; \
      o_[0] = __builtin_amdgcn_perm(lo[1], lo[0], 0x07060302u); \
      o_[1] = __builtin_amdgcn_perm(lo[3], lo[2], 0x07060302u); \
      o_[2] = __builtin_amdgcn_perm(hi[1], hi[0], 0x07060302u); \
      o_[3] = __builtin_amdgcn_perm(hi[3], hi[2], 0x07060302u); \
      dst = __builtin_bit_cast(s16x8, o_); }
    RPK(a0, g0, g1) RPK(a1, g2, g3) RPK(a2, g4, g5) RPK(a3, g6, g7)
    #undef RPK

    // ---- rec partials: c[ct] += y_eighth @ W^T (named accs, no dyn index) ----
    f32x4 c0 = {0,0,0,0}, c1 = {0,0,0,0}, c2 = {0,0,0,0}, c3 = {0,0,0,0};
    f32x4 c4 = {0,0,0,0}, c5 = {0,0,0,0}, c6 = {0,0,0,0}, c7 = {0,0,0,0};
    #define RECK(ak, kc) \
      c0 = __builtin_amdgcn_mfma_f32_16x16x32_bf16(ak, wfrag[0][kc], c0, 0, 0, 0); \
      c1 = __builtin_amdgcn_mfma_f32_16x16x32_bf16(ak, wfrag[1][kc], c1, 0, 0, 0); \
      c2 = __builtin_amdgcn_mfma_f32_16x16x32_bf16(ak, wfrag[2][kc], c2, 0, 0, 0); \
      c3 = __builtin_amdgcn_mfma_f32_16x16x32_bf16(ak, wfrag[3][kc], c3, 0, 0, 0); \
      c4 = __builtin_amdgcn_mfma_f32_16x16x32_bf16(ak, wfrag[4][kc], c4, 0, 0, 0); \
      c5 = __builtin_amdgcn_mfma_f32_16x16x32_bf16(ak, wfrag[5][kc], c5, 0, 0, 0); \
      c6 = __builtin_amdgcn_mfma_f32_16x16x32_bf16(ak, wfrag[6][kc], c6, 0, 0, 0); \
      c7 = __builtin_amdgcn_mfma_f32_16x16x32_bf16(ak, wfrag[7][kc], c7, 0, 0, 0);
    RECK(a0, 0) RECK(a1, 1) RECK(a2, 2) RECK(a3, 3)
    #undef RECK

    // ---- cross-wave reduction (parity LDS, contiguous b128) ----
    f32x4* rb = red + (size_t)p * 512;             // [wv][ct][lane]
    rb[(wv * 8 + 0) * 64 + lane] = c0;  rb[(wv * 8 + 1) * 64 + lane] = c1;
    rb[(wv * 8 + 2) * 64 + lane] = c2;  rb[(wv * 8 + 3) * 64 + lane] = c3;
    rb[(wv * 8 + 4) * 64 + lane] = c4;  rb[(wv * 8 + 5) * 64 + lane] = c5;
    rb[(wv * 8 + 6) * 64 + lane] = c6;  rb[(wv * 8 + 7) * 64 + lane] = c7;
    __syncthreads();
    f32x4 z = uacc;
    #pragma unroll
    for (int w = 0; w < 8; ++w) z += rb[(w * 8 + wv) * 64 + lane];

    // ---- state update + self-tagged publish (fire-and-forget) ----
    const unsigned tag = (unsigned)(t + 1);
    unsigned* pb = pbase + (size_t)pn * PAR_STRIDE;
    #define UPD(r) { \
      float z_ = z[r] + bias; \
      float e_ = __expf(z_ + z_); \
      float th_ = fmaf(-2.0f, __builtin_amdgcn_rcpf(e_ + 1.0f), 1.0f); \
      float yn_ = ys[r] + 0.1f*(th_ - xs[r] - 0.2f*ys[r]); \
      xs[r] += 0.1f*yn_; ys[r] = yn_; \
      unsigned w_ = ((unsigned)f2bf(yn_) << 16) | tag; \
      unsigned* ad_ = pb + (r) * 1024; \
      asm volatile("global_store_dword %0, %1, off sc0 sc1" :: "v"(ad_), "v"(w_) : "memory"); }
    UPD(0) UPD(1) UPD(2) UPD(3)
    #undef UPD

    // ---- prefetch batch A-frags for t+1 (plain cached loads) ----
    {
      const int tn = (t + 1 < T_STEPS) ? (t + 1) : t;
      const unsigned short* bp = batchbf + ((size_t)tn * BATCH_N + g * 16 + l15) * IDIM + kb * 8;
      #pragma unroll
      for (int kc = 0; kc < 4; ++kc) bfr[kc] = *reinterpret_cast<const s16x8*>(bp + kc * 32);
    }
  }

  // ---- write x_T (owned column, 4 rows) ----
  #pragma unroll
  for (int q = 0; q < 4; ++q) {
    int row = g * 16 + kb * 4 + q;
    xT[(size_t)row * NDIM + jc] = xs[q];
  }
}

// ---------------- final readout: out = x_T @ h2o^T + b ----------------
__global__ void horn_out(const float* __restrict__ xT, const float* __restrict__ h2o_w,
                         const float* __restrict__ h2o_b, float* __restrict__ out) {
  int b = blockIdx.x;
  int lane = threadIdx.x;                  // 64 threads
  float p[ODIM];
  #pragma unroll
  for (int o = 0; o < ODIM; ++o) p[o] = 0.f;
  for (int it = 0; it < NDIM / 64; ++it) {
    int n = it * 64 + lane;
    float xv = xT[(size_t)b * NDIM + n];
    #pragma unroll
    for (int o = 0; o < ODIM; ++o) p[o] += xv * h2o_w[o * NDIM + n];
  }
  #pragma unroll
  for (int o = 0; o < ODIM; ++o) {
    float v = p[o];
    #pragma unroll
    for (int off = 32; off >= 1; off >>= 1) v += __shfl_down(v, off, 64);
    if (lane == 0) out[b * ODIM + o] = v + h2o_b[o];
  }
}

__global__ void horn_fail(float* out) {    // loud sentinel if ws too small
  int i = blockIdx.x * 256 + threadIdx.x;
  if (i < BATCH_N * ODIM) out[i] = 12345.0f;
}

extern "C" void kernel_launch(void* const* d_in, const int* in_sizes, int n_in,
                              void* d_out, int out_size, void* d_ws, size_t ws_size,
                              hipStream_t stream) {
  const float* batch = (const float*)d_in[0];
  const float* i2h_w = (const float*)d_in[1];
  const float* i2h_b = (const float*)d_in[2];
  const float* h2h_w = (const float*)d_in[3];
  const float* h2h_b = (const float*)d_in[4];
  const float* h2o_w = (const float*)d_in[5];
  const float* h2o_b = (const float*)d_in[6];
  float* out = (float*)d_out;
  char* ws = (char*)d_ws;

  if (ws_size < WS_NEED) {
    horn_fail<<<16, 256, 0, stream>>>(out);
    return;
  }

  (void)hipFuncSetAttribute(reinterpret_cast<const void*>(horn_persistent),
                            hipFuncAttributeMaxDynamicSharedMemorySize, 163840);

  hipMemsetAsync(ws + YBUF_OFF, 0, YBUF_WORDS * 4, stream);  // tags=0, y_0=0 (both parities)

  horn_convert<<<8192, 256, 0, stream>>>(batch, (unsigned short*)(ws + 0));

  horn_persistent<<<128, THREADS, 163840, stream>>>(
      (const unsigned short*)(ws + 0), i2h_w, i2h_b, h2h_w, h2h_b,
      (unsigned*)(ws + YBUF_OFF), (float*)(ws + XT_OFF));

  horn_out<<<BATCH_N, 64, 0, stream>>>((const float*)(ws + XT_OFF), h2o_w, h2o_b, out);
}